// Round 5
// baseline (615.509 us; speedup 1.0000x reference)
//
#include <hip/hip_runtime.h>
#include <hip/hip_bf16.h>

// Problem constants
constexpr int B_   = 32;
constexpr int CIN  = 64;
constexpr int HIN  = 128;
constexpr int WIN  = 128;
constexpr int COUT = 128;
constexpr int HO   = 126;
constexpr int WO   = 126;
constexpr int HP   = 63;
constexpr int WP   = 63;
constexpr int NG   = 8;
constexpr float EPS = 1e-5f;

typedef _Float16 f16x8 __attribute__((ext_vector_type(8)));
typedef _Float16 f16x2 __attribute__((ext_vector_type(2)));
typedef float    f32x4 __attribute__((ext_vector_type(4)));

// ws layout (bytes):
//   stats @ 0        : 512 floats (pad to 4096)
//   Wh2   @ 4096     : 9*128*64 f16 = 147456 (permuted)   (ends 151552)
//   xh    @ 151552   : 32*128*128*64 f16 = 64 MB          (ends 67260416; +4KB slack)
//   yp    @ 67264512 : 32*128*63*64 f16 = 33 MB (padded wp-stride 64)

// ---------- Prep: W (OIHW fp32) -> Wh2 permuted f16 ----------
// Wh2 flat idx i = (((kk*8 + t)*2 + c)*64 + (q*16+ln))*8 + j
//   holds W[cout = t*16+ln][cin = c*32 + q*8 + j][tap kk]
// so that conv's B-fragment ds_reads are contiguous stride-16B (conflict-free)
// and staging is a straight contiguous copy.
__global__ __launch_bounds__(256)
void whprep_kernel(const float* __restrict__ W, _Float16* __restrict__ Wh2)
{
    int i = blockIdx.x * 256 + threadIdx.x;
    if (i >= 9 * COUT * CIN) return;
    const int j  = i & 7;
    const int l  = (i >> 3) & 63;
    const int ln = l & 15;
    const int q  = l >> 4;
    const int c  = (i >> 9) & 1;
    const int t  = (i >> 10) & 7;
    const int kk = i >> 13;
    Wh2[i] = (_Float16)W[((size_t)(t * 16 + ln) * CIN + c * 32 + q * 8 + j) * 9 + kk];
}

// ---------- Prep: x fp32 NCHW -> xh f16 NHWC (float4 reads) ----------
// grid 512: block = 8 (b,h)-rows; thread (r = tid>>5, f4 = tid&31) handles 4 px x 64 cin.
__global__ __launch_bounds__(256)
void xprep_kernel(const float* __restrict__ x, _Float16* __restrict__ xh)
{
    const int tid = threadIdx.x;
    const int f4  = tid & 31;
    const int r   = tid >> 5;
    const int row = blockIdx.x * 8 + r;          // b*128 + h
    const float* xp = x + (size_t)(row >> 7) * (CIN * HIN * WIN)
                        + (size_t)(row & 127) * WIN + f4 * 4;   // + c*16384
    _Float16* op = xh + ((size_t)row * 128 + f4 * 4) * 64;       // + j*64 + cg*8
    #pragma unroll
    for (int cg = 0; cg < 8; ++cg) {
        float4 v[8];
        #pragma unroll
        for (int jj = 0; jj < 8; ++jj)
            v[jj] = *(const float4*)(xp + (size_t)(cg * 8 + jj) * (HIN * WIN));
        #pragma unroll
        for (int j = 0; j < 4; ++j) {
            f16x8 o;
            #pragma unroll
            for (int jj = 0; jj < 8; ++jj)
                o[jj] = (_Float16)(((const float*)&v[jj])[j]);
            *(f16x8*)(op + j * 64 + cg * 8) = o;
        }
    }
}

// ---------- Conv: implicit GEMM, 16x16x32 MFMA, 4x4 wave tiles ----------
// grid (63 row-pairs, 2 w-halves, 32 batch); block 256 = 4 waves.
// wave (mi = wave&1 -> output row 2rp+mi, ni = wave>>1 -> cout half).
// Wave tile: M = 64 px x N = 64 couts as 4x4 tiles of 16x16; K = 576.
// A: x-tile resident in LDS (staged once). B: per-tap 16KB LDS, double-buffered,
// register-prefetched 2 taps ahead (issued at iteration top -> cheap vmcnt at barrier).
__global__ __launch_bounds__(256, 2)
void conv_mfma_kernel(const _Float16* __restrict__ xh, const _Float16* __restrict__ Wh2,
                      const float* __restrict__ bias, const float* __restrict__ gamma,
                      const float* __restrict__ scale,
                      _Float16* __restrict__ yp, float* __restrict__ stats)
{
    const int tid  = threadIdx.x;
    const int lane = tid & 63;
    const int wave = tid >> 6;
    const int mi   = wave & 1;
    const int ni   = wave >> 1;
    const int ln   = lane & 15;      // m-lane (px) for A, n-lane (cout) for B/D
    const int q    = lane >> 4;      // k-quad
    const int rp   = blockIdx.x;     // 0..62
    const int half = blockIdx.y;     // 0..1
    const int b    = blockIdx.z;

    __shared__ _Float16 sx[4 * 66 * 72];   // 38016 B: [4 rows][66 px][72 cin-pad]
    __shared__ _Float16 bbuf[2][8192];     // 32768 B: per-tap B, unit-contiguous

    // ---- stage A (once): wave w stages input row 2rp+w, px half*64 .. +65 ----
    {
        const size_t grow = ((size_t)(b * 128 + 2 * rp + wave)) * 8192 + (size_t)half * 64 * 64;
        const int pxl = lane >> 3, cb = lane & 7;
        _Float16* dst = sx + wave * 4752;
        #pragma unroll
        for (int it = 0; it < 8; ++it) {
            const int px = it * 8 + pxl;
            *(f16x8*)(dst + px * 72 + cb * 8) = *(const f16x8*)(xh + grow + px * 64 + cb * 8);
        }
        if (lane < 16) {                   // halo px 64,65 (over-read covered by xh slack)
            const int px = 64 + (lane >> 3);
            *(f16x8*)(dst + px * 72 + cb * 8) = *(const f16x8*)(xh + grow + px * 64 + cb * 8);
        }
    }

    // ---- B prefetch: R[0]<-tap0, R[1]<-tap1; write tap0 -> bbuf[0] ----
    const int ubase = wave * 256 + lane;    // unit index base (+ it*64)
    f16x8 R[2][4];
    #pragma unroll
    for (int it = 0; it < 4; ++it) R[0][it] = *(const f16x8*)(Wh2 + (size_t)(ubase + it * 64) * 8);
    #pragma unroll
    for (int it = 0; it < 4; ++it) R[1][it] = *(const f16x8*)(Wh2 + 8192 + (size_t)(ubase + it * 64) * 8);
    #pragma unroll
    for (int it = 0; it < 4; ++it) *(f16x8*)(&bbuf[0][(ubase + it * 64) * 8]) = R[0][it];
    __syncthreads();

    f32x4 acc[4][4] = {};   // [mt][nt]

    for (int kk = 0; kk < 9; ++kk) {
        const int p = kk & 1;
        if (kk < 7) {       // prefetch tap kk+2 into the now-free register set
            #pragma unroll
            for (int it = 0; it < 4; ++it)
                R[p][it] = *(const f16x8*)(Wh2 + (size_t)(kk + 2) * 8192 + (size_t)(ubase + it * 64) * 8);
        }
        const int kh = kk / 3, kw = kk - kh * 3;
        const _Float16* ap = sx + (mi + kh) * 4752 + (ln + kw) * 72 + q * 8;
        #pragma unroll
        for (int chunk = 0; chunk < 2; ++chunk) {
            f16x8 Af[4], Bf[4];
            #pragma unroll
            for (int mt = 0; mt < 4; ++mt)
                Af[mt] = *(const f16x8*)(ap + mt * 16 * 72 + chunk * 32);
            #pragma unroll
            for (int nt = 0; nt < 4; ++nt)
                Bf[nt] = *(const f16x8*)(&bbuf[p][(ni * 4 + nt) * 1024 + chunk * 512 + lane * 8]);
            #pragma unroll
            for (int mt = 0; mt < 4; ++mt)
                #pragma unroll
                for (int nt = 0; nt < 4; ++nt)
                    acc[mt][nt] = __builtin_amdgcn_mfma_f32_16x16x32_f16(Af[mt], Bf[nt], acc[mt][nt], 0, 0, 0);
        }
        if (kk < 8) {       // publish tap kk+1 (loaded one full tap ago) into the other buffer
            #pragma unroll
            for (int it = 0; it < 4; ++it)
                *(f16x8*)(&bbuf[p ^ 1][(ubase + it * 64) * 8]) = R[(kk + 1) & 1][it];
            __syncthreads();
        }
    }

    // ---- epilogue: bias, stats, horizontal pool (register pairs), vertical via LDS ----
    // D layout 16x16: col(cout)=ln, row(px within tile)= q*4 + reg
    float ev[4][4][2];            // [nt][mt][pl]
    float s1[4] = {}, s2[4] = {};
    bool  useMin[4];
    #pragma unroll
    for (int nt = 0; nt < 4; ++nt) {
        const int co = ni * 64 + nt * 16 + ln;
        const float bv = bias[co];
        useMin[nt] = (gamma[co] * scale[co]) < 0.0f;   // affine slope sign (rstd>0)
        #pragma unroll
        for (int mt = 0; mt < 4; ++mt) {
            const float e0 = acc[mt][nt][0] + bv;
            const float e1 = acc[mt][nt][1] + bv;
            const float e2 = acc[mt][nt][2] + bv;
            const float e3 = acc[mt][nt][3] + bv;
            // wo = half*64 + mt*16 + q*4 + r; invalid (>=126) iff half&&mt==3&&q==3, r in {2,3}
            const bool bad = (half == 1) && (mt == 3) && (q == 3);
            s1[nt] += e0 + e1;  s2[nt] += e0 * e0 + e1 * e1;
            if (!bad) { s1[nt] += e2 + e3; s2[nt] += e2 * e2 + e3 * e3; }
            ev[nt][mt][0] = useMin[nt] ? fminf(e0, e1) : fmaxf(e0, e1);
            ev[nt][mt][1] = useMin[nt] ? fminf(e2, e3) : fmaxf(e2, e3);
        }
        // full-wave reduce (16 couts of one group x this wave's 64 px)
        float a1 = s1[nt], a2 = s2[nt];
        #pragma unroll
        for (int off = 1; off < 64; off <<= 1) {
            a1 += __shfl_xor(a1, off);
            a2 += __shfl_xor(a2, off);
        }
        if (lane == 0) {
            const int g = ni * 4 + nt;
            atomicAdd(&stats[((size_t)b * NG + g) * 2 + 0], a1);
            atomicAdd(&stats[((size_t)b * NG + g) * 2 + 1], a2);
        }
    }

    // vertical combine: mi=1 publishes, mi=0 combines + stores yp
    __syncthreads();               // K-loop LDS reads done; reuse sx
    _Float16* ex = sx;             // [(ni*4+nt)*16 + ln][32 pp] f16 = 8 KB
    if (mi == 1) {
        #pragma unroll
        for (int nt = 0; nt < 4; ++nt)
            #pragma unroll
            for (int mt = 0; mt < 4; ++mt)
                *(f16x2*)(ex + (((ni * 4 + nt) * 16 + ln) * 32) + mt * 8 + q * 2) =
                    (f16x2){(_Float16)ev[nt][mt][0], (_Float16)ev[nt][mt][1]};
    }
    __syncthreads();
    if (mi == 0) {
        #pragma unroll
        for (int nt = 0; nt < 4; ++nt) {
            const int co = ni * 64 + nt * 16 + ln;
            _Float16* ypp = yp + ((size_t)(b * COUT + co) * HP + rp) * 64 + half * 32;
            #pragma unroll
            for (int mt = 0; mt < 4; ++mt) {
                const f16x2 o = *(const f16x2*)(ex + (((ni * 4 + nt) * 16 + ln) * 32) + mt * 8 + q * 2);
                const float c0 = useMin[nt] ? fminf(ev[nt][mt][0], (float)o.x)
                                            : fmaxf(ev[nt][mt][0], (float)o.x);
                const float c1 = useMin[nt] ? fminf(ev[nt][mt][1], (float)o.y)
                                            : fmaxf(ev[nt][mt][1], (float)o.y);
                const bool bad = (half == 1) && (mt == 3) && (q == 3);  // wp 63 doesn't exist
                if (!bad)
                    *(f16x2*)(ypp + mt * 8 + q * 2) = (f16x2){(_Float16)c0, (_Float16)c1};
                else
                    ypp[mt * 8 + q * 2] = (_Float16)c0;
            }
        }
    }
}

// ---------- GroupNorm affine + clamp on pre-pooled extrema ----------
__global__ __launch_bounds__(256)
void gn_pool_kernel(const _Float16* __restrict__ yp, const float* __restrict__ stats,
                    const float* __restrict__ gamma, const float* __restrict__ beta,
                    const float* __restrict__ scale, float* __restrict__ out)
{
    const int idx = blockIdx.x * 256 + threadIdx.x;
    if (idx >= B_ * COUT * HP * WP) return;
    const int wp = idx % WP;
    const int hp = (idx / WP) % HP;
    const int c  = (idx / (WP * HP)) % COUT;
    const int b  = idx / (WP * HP * COUT);
    const int g  = c >> 4;

    const float s1 = stats[((size_t)b * NG + g) * 2 + 0];
    const float s2 = stats[((size_t)b * NG + g) * 2 + 1];
    constexpr float inv = 1.0f / (float)((COUT / NG) * HO * WO);
    const float mean = s1 * inv;
    const float var  = fmaf(-mean, mean, s2 * inv);
    const float rstd = rsqrtf(var + EPS);
    const float sc   = scale[c];
    const float a    = rstd * gamma[c] * sc;
    const float bb   = fmaf(-mean, rstd * gamma[c], beta[c]) * sc;

    const float v = (float)yp[((size_t)(b * COUT + c) * HP + hp) * 64 + wp];
    float m = fmaf(v, a, bb);
    m = fminf(fmaxf(m, 0.0f), 1.0f);
    out[idx] = m;
}

extern "C" void kernel_launch(void* const* d_in, const int* in_sizes, int n_in,
                              void* d_out, int out_size, void* d_ws, size_t ws_size,
                              hipStream_t stream)
{
    const float* x     = (const float*)d_in[0];
    const float* W     = (const float*)d_in[1];
    const float* bias  = (const float*)d_in[2];
    const float* scale = (const float*)d_in[3];
    const float* gamma = (const float*)d_in[4];
    const float* beta  = (const float*)d_in[5];

    float*    stats = (float*)d_ws;
    _Float16* Wh2   = (_Float16*)((char*)d_ws + 4096);
    _Float16* xh    = (_Float16*)((char*)d_ws + 151552);
    _Float16* yp    = (_Float16*)((char*)d_ws + 67264512);
    float*    out   = (float*)d_out;

    hipMemsetAsync(stats, 0, B_ * NG * 2 * sizeof(float), stream);

    whprep_kernel<<<(9 * COUT * CIN + 255) / 256, 256, 0, stream>>>(W, Wh2);
    xprep_kernel<<<512, 256, 0, stream>>>(x, xh);
    conv_mfma_kernel<<<dim3(63, 2, B_), 256, 0, stream>>>(xh, Wh2, bias, gamma, scale, yp, stats);

    const int total = B_ * COUT * HP * WP;
    gn_pool_kernel<<<(total + 255) / 256, 256, 0, stream>>>(yp, stats, gamma, beta, scale, out);
}